// Round 1
// baseline (1525.132 us; speedup 1.0000x reference)
//
#include <hip/hip_runtime.h>

// GPT-OSS MoE MLP on MI355X (gfx950).
// E=16 experts, H=I=2048, T=1024 tokens, top-4 routing, BLK=32 dequant blocks.
// Strategy: route -> pack token slots per expert -> bf16 MFMA GEMMs with
// dequant (fp32 block * scale -> bf16) fused into the global->LDS staging.
// Workspace use: ~52.1 MB (xb 4MB, gbuf/ubuf/hbuf 16MB each, routing tables 64KB).

#define HD 2048
#define ID 2048
#define NE 16
#define NT 1024
#define NTOPK 4
#define NSLOTS (NT * NTOPK)   // 4096, exact (each token -> exactly 4 experts)

typedef unsigned short u16;
typedef __attribute__((ext_vector_type(8))) short short8;
typedef __attribute__((ext_vector_type(4))) float f32x4;

__device__ __forceinline__ float bf2f(u16 v) {
    return __uint_as_float(((unsigned)v) << 16);
}
__device__ __forceinline__ u16 f2bf(float f) {
    unsigned u = __float_as_uint(f);
    return (u16)((u + 0x7fffu + ((u >> 16) & 1u)) >> 16);
}

// ---------------- Kernel 1: router (exact f32) + x -> bf16 ----------------
__global__ void router_kernel(const float* __restrict__ x,
                              const float* __restrict__ rw,
                              const float* __restrict__ rb,
                              u16* __restrict__ xb,
                              int* __restrict__ counts,
                              int* __restrict__ topi,
                              float* __restrict__ topv) {
    const int t = blockIdx.x;
    const int lane = threadIdx.x;  // 64 threads = 1 wave

    float xr[32];
#pragma unroll
    for (int j = 0; j < 32; ++j) xr[j] = x[(size_t)t * HD + j * 64 + lane];
#pragma unroll
    for (int j = 0; j < 32; ++j) xb[(size_t)t * HD + j * 64 + lane] = f2bf(xr[j]);

    float lg[NE];
#pragma unroll
    for (int e = 0; e < NE; ++e) {
        const float* w = rw + (size_t)e * HD;
        float s = 0.f;
#pragma unroll
        for (int j = 0; j < 32; ++j) s = fmaf(xr[j], w[j * 64 + lane], s);
        // full-wave butterfly reduce
        for (int off = 32; off > 0; off >>= 1) s += __shfl_xor(s, off);
        lg[e] = s + rb[e];
    }

    if (lane == 0) {
        unsigned used = 0;
        float sv[NTOPK];
        int si[NTOPK];
#pragma unroll
        for (int k = 0; k < NTOPK; ++k) {
            float best = -1e30f;
            int bi = 0;
#pragma unroll
            for (int e = 0; e < NE; ++e) {
                if (!(used & (1u << e)) && lg[e] > best) { best = lg[e]; bi = e; }
            }
            used |= 1u << bi;
            sv[k] = best;
            si[k] = bi;
        }
        const float mx = sv[0];
        float p[NTOPK], sum = 0.f;
#pragma unroll
        for (int k = 0; k < NTOPK; ++k) { p[k] = __expf(sv[k] - mx); sum += p[k]; }
        const float inv = 1.0f / sum;
#pragma unroll
        for (int k = 0; k < NTOPK; ++k) {
            atomicAdd(&counts[si[k]], 1);
            topi[t * NTOPK + k] = si[k];
            topv[t * NTOPK + k] = p[k] * inv;
        }
    }
}

// ---------------- Kernel 2: exclusive prefix over counts ----------------
__global__ void bases_kernel(const int* __restrict__ counts, int* __restrict__ bases) {
    if (threadIdx.x == 0) {
        int acc = 0;
#pragma unroll
        for (int e = 0; e < NE; ++e) { bases[e] = acc; acc += counts[e]; }
    }
}

// ---------------- Kernel 3: slot assignment ----------------
__global__ void assign_kernel(const int* __restrict__ topi, const float* __restrict__ topv,
                              const int* __restrict__ bases, int* __restrict__ cursor,
                              int* __restrict__ tok_slot, float* __restrict__ wgt_slot) {
    const int t = blockIdx.x * 256 + threadIdx.x;
    if (t < NT) {
#pragma unroll
        for (int k = 0; k < NTOPK; ++k) {
            const int e = topi[t * NTOPK + k];
            const int s = atomicAdd(&cursor[e], 1);
            const int slot = bases[e] + s;
            tok_slot[slot] = t;
            wgt_slot[slot] = topv[t * NTOPK + k];
        }
    }
}

// ---------------- Kernel 4: gate/up GEMM (M=256, N=64, BK=32) ----------------
// grid: (ID/64, 4 mtiles, NE*2); block: 256 (4 waves, 64x64 wave-tiles).
__global__ __launch_bounds__(256, 2) void gu_gemm(
    const u16* __restrict__ xb,
    const float* __restrict__ gate_blocks, const float* __restrict__ gate_scales,
    const float* __restrict__ gate_bias,
    const float* __restrict__ up_blocks, const float* __restrict__ up_scales,
    const float* __restrict__ up_bias,
    const int* __restrict__ counts, const int* __restrict__ bases,
    const int* __restrict__ tok_slot,
    u16* __restrict__ gbuf, u16* __restrict__ ubuf) {
    const int e = blockIdx.z >> 1, mat = blockIdx.z & 1;
    const int n_e = counts[e];
    const int mt = blockIdx.y;
    if (mt * 256 >= n_e) return;
    const int rows = min(256, n_e - mt * 256);
    const int base = bases[e] + mt * 256;
    const float* wb = mat ? up_blocks : gate_blocks;
    const float* wsc = mat ? up_scales : gate_scales;
    const float* wbias = mat ? up_bias : gate_bias;
    u16* outb = mat ? ubuf : gbuf;
    const int n0 = blockIdx.x * 64;

    __shared__ __align__(16) short Asl[4][256][8];  // 16 KB  [kchunk][row][8]
    __shared__ __align__(16) short Bsl[4][64][8];   //  4 KB  [kchunk][col][8]

    const int tid = threadIdx.x;
    const int wave = tid >> 6, lane = tid & 63;

    // A staging: thread <-> row (gather by token)
    const int tokA = tok_slot[base + min(tid, rows - 1)];
    const u16* aptr = xb + (size_t)tokA * HD;
    // B staging: bn = col (0..63), bq = kchunk (0..3) -> conflict-free LDS writes
    const int bn = tid & 63, bq = tid >> 6;
    const float* bptr = wb + ((size_t)e * ID + n0 + bn) * HD + bq * 8;
    const float* sptr = wsc + ((size_t)e * ID + n0 + bn) * (HD / 32);

    f32x4 acc[4][4];
#pragma unroll
    for (int a = 0; a < 4; ++a)
#pragma unroll
        for (int b = 0; b < 4; ++b) acc[a][b] = (f32x4){0.f, 0.f, 0.f, 0.f};

    int4 areg0, areg1, areg2, areg3;
    float4 br0, br1;
    float sreg;
    {
        const int4* ap = (const int4*)aptr;
        areg0 = ap[0]; areg1 = ap[1]; areg2 = ap[2]; areg3 = ap[3];
        const float4* bp = (const float4*)bptr;
        br0 = bp[0]; br1 = bp[1];
        sreg = sptr[0];
    }

    for (int kb = 0; kb < 64; ++kb) {
        __syncthreads();
        *(int4*)&Asl[0][tid][0] = areg0;
        *(int4*)&Asl[1][tid][0] = areg1;
        *(int4*)&Asl[2][tid][0] = areg2;
        *(int4*)&Asl[3][tid][0] = areg3;
        {
            const int p0 = (int)((unsigned)f2bf(br0.x * sreg) | ((unsigned)f2bf(br0.y * sreg) << 16));
            const int p1 = (int)((unsigned)f2bf(br0.z * sreg) | ((unsigned)f2bf(br0.w * sreg) << 16));
            const int p2 = (int)((unsigned)f2bf(br1.x * sreg) | ((unsigned)f2bf(br1.y * sreg) << 16));
            const int p3 = (int)((unsigned)f2bf(br1.z * sreg) | ((unsigned)f2bf(br1.w * sreg) << 16));
            *(int4*)&Bsl[bq][bn][0] = make_int4(p0, p1, p2, p3);
        }
        __syncthreads();
        if (kb < 63) {  // prefetch next K-step while MFMAs run
            const int4* ap = (const int4*)(aptr + (kb + 1) * 32);
            areg0 = ap[0]; areg1 = ap[1]; areg2 = ap[2]; areg3 = ap[3];
            const float4* bp = (const float4*)(bptr + (kb + 1) * 32);
            br0 = bp[0]; br1 = bp[1];
            sreg = sptr[kb + 1];
        }
        const int kch = lane >> 4, lr = lane & 15;
        short8 af[4], bfv[4];
#pragma unroll
        for (int mi = 0; mi < 4; ++mi)
            af[mi] = *(const short8*)&Asl[kch][wave * 64 + mi * 16 + lr][0];
#pragma unroll
        for (int ni = 0; ni < 4; ++ni)
            bfv[ni] = *(const short8*)&Bsl[kch][ni * 16 + lr][0];
#pragma unroll
        for (int mi = 0; mi < 4; ++mi)
#pragma unroll
            for (int ni = 0; ni < 4; ++ni)
                acc[mi][ni] = __builtin_amdgcn_mfma_f32_16x16x32_bf16(af[mi], bfv[ni], acc[mi][ni], 0, 0, 0);
    }

    // epilogue: C[m = (lane>>4)*4+reg][n = lane&15]  (m89-verified layout)
    const int lr = lane & 15, qq = lane >> 4;
#pragma unroll
    for (int ni = 0; ni < 4; ++ni) {
        const int col = n0 + ni * 16 + lr;
        const float bv = wbias[e * ID + col];
#pragma unroll
        for (int mi = 0; mi < 4; ++mi)
#pragma unroll
            for (int j = 0; j < 4; ++j) {
                const int ml = wave * 64 + mi * 16 + qq * 4 + j;
                if (ml < rows) outb[(size_t)(base + ml) * ID + col] = f2bf(acc[mi][ni][j] + bv);
            }
    }
}

// ---------------- Kernel 5: GLU activation ----------------
__global__ void act_kernel(const u16* __restrict__ g, const u16* __restrict__ u,
                           u16* __restrict__ h) {
    const size_t i = (size_t)blockIdx.x * 256 + threadIdx.x;  // vec8 index
    const int4 gv = ((const int4*)g)[i];
    const int4 uv = ((const int4*)u)[i];
    const int gi[4] = {gv.x, gv.y, gv.z, gv.w};
    const int ui[4] = {uv.x, uv.y, uv.z, uv.w};
    int hi[4];
#pragma unroll
    for (int c = 0; c < 4; ++c) {
        float res[2];
#pragma unroll
        for (int p = 0; p < 2; ++p) {
            float gg = bf2f((u16)(((unsigned)gi[c] >> (16 * p)) & 0xffffu));
            float uu = bf2f((u16)(((unsigned)ui[c] >> (16 * p)) & 0xffffu));
            gg = fminf(gg, 7.0f);
            uu = fminf(fmaxf(uu, -7.0f), 7.0f);
            const float sig = 1.0f / (1.0f + __expf(-1.702f * gg));
            res[p] = (uu + 1.0f) * (gg * sig);
        }
        hi[c] = (int)((unsigned)f2bf(res[0]) | ((unsigned)f2bf(res[1]) << 16));
    }
    ((int4*)h)[i] = make_int4(hi[0], hi[1], hi[2], hi[3]);
}

// ---------------- Kernel 6: down GEMM + weighted scatter ----------------
__global__ __launch_bounds__(256, 2) void down_gemm(
    const u16* __restrict__ hbuf,
    const float* __restrict__ down_blocks, const float* __restrict__ down_scales,
    const float* __restrict__ down_bias,
    const int* __restrict__ counts, const int* __restrict__ bases,
    const int* __restrict__ tok_slot, const float* __restrict__ wgt_slot,
    float* __restrict__ out) {
    const int e = blockIdx.z;
    const int n_e = counts[e];
    const int mt = blockIdx.y;
    if (mt * 256 >= n_e) return;
    const int rows = min(256, n_e - mt * 256);
    const int base = bases[e] + mt * 256;
    const int n0 = blockIdx.x * 64;

    __shared__ __align__(16) short Asl[4][256][8];
    __shared__ __align__(16) short Bsl[4][64][8];

    const int tid = threadIdx.x;
    const int wave = tid >> 6, lane = tid & 63;

    const int slotA = min(base + tid, NSLOTS - 1);
    const u16* aptr = hbuf + (size_t)slotA * ID;
    const int bn = tid & 63, bq = tid >> 6;
    const float* bptr = down_blocks + ((size_t)e * HD + n0 + bn) * ID + bq * 8;
    const float* sptr = down_scales + ((size_t)e * HD + n0 + bn) * (ID / 32);

    f32x4 acc[4][4];
#pragma unroll
    for (int a = 0; a < 4; ++a)
#pragma unroll
        for (int b = 0; b < 4; ++b) acc[a][b] = (f32x4){0.f, 0.f, 0.f, 0.f};

    int4 areg0, areg1, areg2, areg3;
    float4 br0, br1;
    float sreg;
    {
        const int4* ap = (const int4*)aptr;
        areg0 = ap[0]; areg1 = ap[1]; areg2 = ap[2]; areg3 = ap[3];
        const float4* bp = (const float4*)bptr;
        br0 = bp[0]; br1 = bp[1];
        sreg = sptr[0];
    }

    for (int kb = 0; kb < 64; ++kb) {
        __syncthreads();
        *(int4*)&Asl[0][tid][0] = areg0;
        *(int4*)&Asl[1][tid][0] = areg1;
        *(int4*)&Asl[2][tid][0] = areg2;
        *(int4*)&Asl[3][tid][0] = areg3;
        {
            const int p0 = (int)((unsigned)f2bf(br0.x * sreg) | ((unsigned)f2bf(br0.y * sreg) << 16));
            const int p1 = (int)((unsigned)f2bf(br0.z * sreg) | ((unsigned)f2bf(br0.w * sreg) << 16));
            const int p2 = (int)((unsigned)f2bf(br1.x * sreg) | ((unsigned)f2bf(br1.y * sreg) << 16));
            const int p3 = (int)((unsigned)f2bf(br1.z * sreg) | ((unsigned)f2bf(br1.w * sreg) << 16));
            *(int4*)&Bsl[bq][bn][0] = make_int4(p0, p1, p2, p3);
        }
        __syncthreads();
        if (kb < 63) {
            const int4* ap = (const int4*)(aptr + (kb + 1) * 32);
            areg0 = ap[0]; areg1 = ap[1]; areg2 = ap[2]; areg3 = ap[3];
            const float4* bp = (const float4*)(bptr + (kb + 1) * 32);
            br0 = bp[0]; br1 = bp[1];
            sreg = sptr[kb + 1];
        }
        const int kch = lane >> 4, lr = lane & 15;
        short8 af[4], bfv[4];
#pragma unroll
        for (int mi = 0; mi < 4; ++mi)
            af[mi] = *(const short8*)&Asl[kch][wave * 64 + mi * 16 + lr][0];
#pragma unroll
        for (int ni = 0; ni < 4; ++ni)
            bfv[ni] = *(const short8*)&Bsl[kch][ni * 16 + lr][0];
#pragma unroll
        for (int mi = 0; mi < 4; ++mi)
#pragma unroll
            for (int ni = 0; ni < 4; ++ni)
                acc[mi][ni] = __builtin_amdgcn_mfma_f32_16x16x32_bf16(af[mi], bfv[ni], acc[mi][ni], 0, 0, 0);
    }

    const int lr = lane & 15, qq = lane >> 4;
    float bvs[4];
#pragma unroll
    for (int ni = 0; ni < 4; ++ni) bvs[ni] = down_bias[e * HD + n0 + ni * 16 + lr];
#pragma unroll
    for (int mi = 0; mi < 4; ++mi)
#pragma unroll
        for (int j = 0; j < 4; ++j) {
            const int ml = wave * 64 + mi * 16 + qq * 4 + j;
            if (ml >= rows) continue;
            const int slot = base + ml;
            const int tok = tok_slot[slot];
            const float wg = wgt_slot[slot];
            float* orow = out + (size_t)tok * HD;
#pragma unroll
            for (int ni = 0; ni < 4; ++ni)
                atomicAdd(&orow[n0 + ni * 16 + lr], wg * (acc[mi][ni][j] + bvs[ni]));
        }
}

extern "C" void kernel_launch(void* const* d_in, const int* in_sizes, int n_in,
                              void* d_out, int out_size, void* d_ws, size_t ws_size,
                              hipStream_t stream) {
    const float* x           = (const float*)d_in[0];
    const float* rw          = (const float*)d_in[1];
    const float* rb          = (const float*)d_in[2];
    const float* gate_blocks = (const float*)d_in[3];
    const float* gate_scales = (const float*)d_in[4];
    const float* gate_bias   = (const float*)d_in[5];
    const float* up_blocks   = (const float*)d_in[6];
    const float* up_scales   = (const float*)d_in[7];
    const float* up_bias     = (const float*)d_in[8];
    const float* down_blocks = (const float*)d_in[9];
    const float* down_scales = (const float*)d_in[10];
    const float* down_bias   = (const float*)d_in[11];
    float* out = (float*)d_out;

    char* ws = (char*)d_ws;
    // workspace layout (~52.1 MB)
    u16* xb     = (u16*)ws;                      //  4 MB
    u16* gbuf   = (u16*)(ws + (4 << 20));        // 16 MB
    u16* ubuf   = (u16*)(ws + (20 << 20));       // 16 MB
    u16* hbuf   = (u16*)(ws + (36 << 20));       // 16 MB
    int* counts = (int*)(ws + (52 << 20));       // 16
    int* cursor = counts + 16;                   // 16
    int* basesp = counts + 32;                   // 16
    int* topi   = counts + 64;                   // 4096
    float* topv = (float*)(counts + 64 + 4096);  // 4096
    int* tok_slot = (int*)(counts + 64 + 8192);  // 4096
    float* wgt_slot = (float*)(counts + 64 + 12288);

    hipMemsetAsync(d_out, 0, (size_t)NT * HD * sizeof(float), stream);
    hipMemsetAsync(counts, 0, 128, stream);  // counts + cursor

    router_kernel<<<NT, 64, 0, stream>>>(x, rw, rb, xb, counts, topi, topv);
    bases_kernel<<<1, 64, 0, stream>>>(counts, basesp);
    assign_kernel<<<NT / 256, 256, 0, stream>>>(topi, topv, basesp, cursor, tok_slot, wgt_slot);
    gu_gemm<<<dim3(ID / 64, 4, NE * 2), 256, 0, stream>>>(
        xb, gate_blocks, gate_scales, gate_bias, up_blocks, up_scales, up_bias,
        counts, basesp, tok_slot, gbuf, ubuf);
    act_kernel<<<(NSLOTS * ID / 8) / 256, 256, 0, stream>>>(gbuf, ubuf, hbuf);
    down_gemm<<<dim3(HD / 64, 4, NE), 256, 0, stream>>>(
        hbuf, down_blocks, down_scales, down_bias, counts, basesp, tok_slot, wgt_slot, out);
}

// Round 2
// 1278.889 us; speedup vs baseline: 1.1925x; 1.1925x over previous
//
#include <hip/hip_runtime.h>

// GPT-OSS MoE MLP on MI355X (gfx950).
// Round 2: latency-bound K-loop fixed. BK=64/iter, LDS double-buffered B
// (single barrier/iter, global->use distance ~2 iters), A fragments direct
// global->register (xb/hbuf are L2-resident). Weights streamed once (BW floor
// ~122 us for all fp32 weights).

#define HD 2048
#define ID 2048
#define NE 16
#define NT 1024
#define NTOPK 4
#define NSLOTS (NT * NTOPK)   // 4096, exact

typedef unsigned short u16;
typedef __attribute__((ext_vector_type(8))) short short8;
typedef __attribute__((ext_vector_type(4))) float f32x4;

__device__ __forceinline__ float bf2f(u16 v) {
    return __uint_as_float(((unsigned)v) << 16);
}
__device__ __forceinline__ u16 f2bf(float f) {
    unsigned u = __float_as_uint(f);
    return (u16)((u + 0x7fffu + ((u >> 16) & 1u)) >> 16);
}

// ---------------- Kernel 1: router (exact f32) + x -> bf16 ----------------
__global__ void router_kernel(const float* __restrict__ x,
                              const float* __restrict__ rw,
                              const float* __restrict__ rb,
                              u16* __restrict__ xb,
                              int* __restrict__ counts,
                              int* __restrict__ topi,
                              float* __restrict__ topv) {
    const int t = blockIdx.x;
    const int lane = threadIdx.x;  // 64 threads = 1 wave

    float xr[32];
#pragma unroll
    for (int j = 0; j < 32; ++j) xr[j] = x[(size_t)t * HD + j * 64 + lane];
#pragma unroll
    for (int j = 0; j < 32; ++j) xb[(size_t)t * HD + j * 64 + lane] = f2bf(xr[j]);

    float lg[NE];
#pragma unroll
    for (int e = 0; e < NE; ++e) {
        const float* w = rw + (size_t)e * HD;
        float s = 0.f;
#pragma unroll
        for (int j = 0; j < 32; ++j) s = fmaf(xr[j], w[j * 64 + lane], s);
        for (int off = 32; off > 0; off >>= 1) s += __shfl_xor(s, off);
        lg[e] = s + rb[e];
    }

    if (lane == 0) {
        unsigned used = 0;
        float sv[NTOPK];
        int si[NTOPK];
#pragma unroll
        for (int k = 0; k < NTOPK; ++k) {
            float best = -1e30f;
            int bi = 0;
#pragma unroll
            for (int e = 0; e < NE; ++e) {
                if (!(used & (1u << e)) && lg[e] > best) { best = lg[e]; bi = e; }
            }
            used |= 1u << bi;
            sv[k] = best;
            si[k] = bi;
        }
        const float mx = sv[0];
        float p[NTOPK], sum = 0.f;
#pragma unroll
        for (int k = 0; k < NTOPK; ++k) { p[k] = __expf(sv[k] - mx); sum += p[k]; }
        const float inv = 1.0f / sum;
#pragma unroll
        for (int k = 0; k < NTOPK; ++k) {
            atomicAdd(&counts[si[k]], 1);
            topi[t * NTOPK + k] = si[k];
            topv[t * NTOPK + k] = p[k] * inv;
        }
    }
}

// ---------------- Kernel 2: exclusive prefix over counts ----------------
__global__ void bases_kernel(const int* __restrict__ counts, int* __restrict__ bases) {
    if (threadIdx.x == 0) {
        int acc = 0;
#pragma unroll
        for (int e = 0; e < NE; ++e) { bases[e] = acc; acc += counts[e]; }
    }
}

// ---------------- Kernel 3: slot assignment ----------------
__global__ void assign_kernel(const int* __restrict__ topi, const float* __restrict__ topv,
                              const int* __restrict__ bases, int* __restrict__ cursor,
                              int* __restrict__ tok_slot, float* __restrict__ wgt_slot) {
    const int t = blockIdx.x * 256 + threadIdx.x;
    if (t < NT) {
#pragma unroll
        for (int k = 0; k < NTOPK; ++k) {
            const int e = topi[t * NTOPK + k];
            const int s = atomicAdd(&cursor[e], 1);
            const int slot = bases[e] + s;
            tok_slot[slot] = t;
            wgt_slot[slot] = topv[t * NTOPK + k];
        }
    }
}

// ---------------- Kernel 4: gate/up GEMM (M=256, N=64, BK=64, dbuf B) ------
// grid: (ID/64 ntiles, 4 mtiles, NE*2); block: 256 (4 waves stacked on M).
__global__ __launch_bounds__(256, 2) void gu_gemm(
    const u16* __restrict__ xb,
    const float* __restrict__ gate_blocks, const float* __restrict__ gate_scales,
    const float* __restrict__ gate_bias,
    const float* __restrict__ up_blocks, const float* __restrict__ up_scales,
    const float* __restrict__ up_bias,
    const int* __restrict__ counts, const int* __restrict__ bases,
    const int* __restrict__ tok_slot,
    u16* __restrict__ gbuf, u16* __restrict__ ubuf) {
    const int e = blockIdx.z >> 1, mat = blockIdx.z & 1;
    const int n_e = counts[e];
    const int mt = blockIdx.y;
    if (mt * 256 >= n_e) return;
    const int rows = min(256, n_e - mt * 256);
    const int base = bases[e] + mt * 256;
    const float* wb = mat ? up_blocks : gate_blocks;
    const float* wsc = mat ? up_scales : gate_scales;
    const float* wbias = mat ? up_bias : gate_bias;
    u16* outb = mat ? ubuf : gbuf;
    const int n0 = blockIdx.x * 64;

    // B double buffer: [buf][kchunk(8 of 8 k-elems)][col(64)][8 bf16] = 16 KB
    __shared__ __align__(16) short Bsl[2][8][64][8];

    const int tid = threadIdx.x;
    const int wave = tid >> 6, lane = tid & 63;
    const int lr = lane & 15, kch = lane >> 4;

    // A fragment base pointers (direct global, per-lane; includes kch*8)
    const u16* ap[4];
#pragma unroll
    for (int mi = 0; mi < 4; ++mi) {
        const int m = wave * 64 + mi * 16 + lr;
        const int tok = tok_slot[base + min(m, rows - 1)];
        ap[mi] = xb + (size_t)tok * HD + kch * 8;
    }

    // B staging role: thread -> (col, quarter q of 16 k-elems)
    const int col = tid & 63, q = tid >> 6;
    const float* bptr = wb + ((size_t)e * ID + n0 + col) * HD + q * 16;
    const float* sptr = wsc + ((size_t)e * ID + n0 + col) * (HD / 32);

    f32x4 acc[4][4];
#pragma unroll
    for (int a = 0; a < 4; ++a)
#pragma unroll
        for (int b = 0; b < 4; ++b) acc[a][b] = (f32x4){0.f, 0.f, 0.f, 0.f};

    float4 br0, br1, br2, br3;
    float sc;
#define LOADB(KB)                                                    \
    {                                                                \
        const float4* p = (const float4*)(bptr + (KB) * 64);         \
        br0 = p[0]; br1 = p[1]; br2 = p[2]; br3 = p[3];              \
        sc = sptr[(KB) * 2 + (q >> 1)];                              \
    }
#define WRITEB(BUF)                                                  \
    {                                                                \
        short8 lo, hi;                                               \
        lo[0] = (short)f2bf(br0.x * sc); lo[1] = (short)f2bf(br0.y * sc); \
        lo[2] = (short)f2bf(br0.z * sc); lo[3] = (short)f2bf(br0.w * sc); \
        lo[4] = (short)f2bf(br1.x * sc); lo[5] = (short)f2bf(br1.y * sc); \
        lo[6] = (short)f2bf(br1.z * sc); lo[7] = (short)f2bf(br1.w * sc); \
        hi[0] = (short)f2bf(br2.x * sc); hi[1] = (short)f2bf(br2.y * sc); \
        hi[2] = (short)f2bf(br2.z * sc); hi[3] = (short)f2bf(br2.w * sc); \
        hi[4] = (short)f2bf(br3.x * sc); hi[5] = (short)f2bf(br3.y * sc); \
        hi[6] = (short)f2bf(br3.z * sc); hi[7] = (short)f2bf(br3.w * sc); \
        *(short8*)&Bsl[BUF][q * 2][col][0] = lo;                     \
        *(short8*)&Bsl[BUF][q * 2 + 1][col][0] = hi;                 \
    }

    LOADB(0);
    WRITEB(0);
    LOADB(1);
    __syncthreads();

    for (int kb = 0; kb < 32; ++kb) {
        // A fragments for this iteration (L2-resident source)
        short8 a0[4], a1[4];
#pragma unroll
        for (int mi = 0; mi < 4; ++mi) {
            a0[mi] = *(const short8*)(ap[mi] + kb * 64);
            a1[mi] = *(const short8*)(ap[mi] + kb * 64 + 32);
        }
        // stage B(kb+1) into the other buffer; issue loads for B(kb+2)
        if (kb + 1 < 32) {
            WRITEB((kb + 1) & 1);
            if (kb + 2 < 32) LOADB(kb + 2);
        }
        // B fragments from current buffer
        const int buf = kb & 1;
        short8 bfv[2][4];
#pragma unroll
        for (int s = 0; s < 2; ++s)
#pragma unroll
            for (int ni = 0; ni < 4; ++ni)
                bfv[s][ni] = *(const short8*)&Bsl[buf][s * 4 + kch][ni * 16 + lr][0];
#pragma unroll
        for (int mi = 0; mi < 4; ++mi)
#pragma unroll
            for (int ni = 0; ni < 4; ++ni)
                acc[mi][ni] = __builtin_amdgcn_mfma_f32_16x16x32_bf16(a0[mi], bfv[0][ni], acc[mi][ni], 0, 0, 0);
#pragma unroll
        for (int mi = 0; mi < 4; ++mi)
#pragma unroll
            for (int ni = 0; ni < 4; ++ni)
                acc[mi][ni] = __builtin_amdgcn_mfma_f32_16x16x32_bf16(a1[mi], bfv[1][ni], acc[mi][ni], 0, 0, 0);
        __syncthreads();
    }
#undef LOADB
#undef WRITEB

    // epilogue: C[m = (lane>>4)*4+reg][n = lane&15] (m89-verified layout)
    const int qq = lane >> 4;
#pragma unroll
    for (int ni = 0; ni < 4; ++ni) {
        const int colo = n0 + ni * 16 + lr;
        const float bv = wbias[e * ID + colo];
#pragma unroll
        for (int mi = 0; mi < 4; ++mi)
#pragma unroll
            for (int j = 0; j < 4; ++j) {
                const int ml = wave * 64 + mi * 16 + qq * 4 + j;
                if (ml < rows) outb[(size_t)(base + ml) * ID + colo] = f2bf(acc[mi][ni][j] + bv);
            }
    }
}

// ---------------- Kernel 5: GLU activation ----------------
__global__ void act_kernel(const u16* __restrict__ g, const u16* __restrict__ u,
                           u16* __restrict__ h) {
    const size_t i = (size_t)blockIdx.x * 256 + threadIdx.x;  // vec8 index
    const int4 gv = ((const int4*)g)[i];
    const int4 uv = ((const int4*)u)[i];
    const int gi[4] = {gv.x, gv.y, gv.z, gv.w};
    const int ui[4] = {uv.x, uv.y, uv.z, uv.w};
    int hi[4];
#pragma unroll
    for (int c = 0; c < 4; ++c) {
        float res[2];
#pragma unroll
        for (int p = 0; p < 2; ++p) {
            float gg = bf2f((u16)(((unsigned)gi[c] >> (16 * p)) & 0xffffu));
            float uu = bf2f((u16)(((unsigned)ui[c] >> (16 * p)) & 0xffffu));
            gg = fminf(gg, 7.0f);
            uu = fminf(fmaxf(uu, -7.0f), 7.0f);
            const float sig = 1.0f / (1.0f + __expf(-1.702f * gg));
            res[p] = (uu + 1.0f) * (gg * sig);
        }
        hi[c] = (int)((unsigned)f2bf(res[0]) | ((unsigned)f2bf(res[1]) << 16));
    }
    ((int4*)h)[i] = make_int4(hi[0], hi[1], hi[2], hi[3]);
}

// ---------------- Kernel 6: down GEMM + weighted scatter -------------------
__global__ __launch_bounds__(256, 2) void down_gemm(
    const u16* __restrict__ hbuf,
    const float* __restrict__ down_blocks, const float* __restrict__ down_scales,
    const float* __restrict__ down_bias,
    const int* __restrict__ counts, const int* __restrict__ bases,
    const int* __restrict__ tok_slot, const float* __restrict__ wgt_slot,
    float* __restrict__ out) {
    const int e = blockIdx.z;
    const int n_e = counts[e];
    const int mt = blockIdx.y;
    if (mt * 256 >= n_e) return;
    const int rows = min(256, n_e - mt * 256);
    const int base = bases[e] + mt * 256;
    const int n0 = blockIdx.x * 64;

    __shared__ __align__(16) short Bsl[2][8][64][8];

    const int tid = threadIdx.x;
    const int wave = tid >> 6, lane = tid & 63;
    const int lr = lane & 15, kch = lane >> 4;

    const u16* ap[4];
#pragma unroll
    for (int mi = 0; mi < 4; ++mi) {
        const int m = wave * 64 + mi * 16 + lr;
        const int slot = base + min(m, rows - 1);
        ap[mi] = hbuf + (size_t)slot * ID + kch * 8;
    }

    const int col = tid & 63, q = tid >> 6;
    const float* bptr = down_blocks + ((size_t)e * HD + n0 + col) * ID + q * 16;
    const float* sptr = down_scales + ((size_t)e * HD + n0 + col) * (ID / 32);

    f32x4 acc[4][4];
#pragma unroll
    for (int a = 0; a < 4; ++a)
#pragma unroll
        for (int b = 0; b < 4; ++b) acc[a][b] = (f32x4){0.f, 0.f, 0.f, 0.f};

    float4 br0, br1, br2, br3;
    float sc;
#define LOADB(KB)                                                    \
    {                                                                \
        const float4* p = (const float4*)(bptr + (KB) * 64);         \
        br0 = p[0]; br1 = p[1]; br2 = p[2]; br3 = p[3];              \
        sc = sptr[(KB) * 2 + (q >> 1)];                              \
    }
#define WRITEB(BUF)                                                  \
    {                                                                \
        short8 lo, hi;                                               \
        lo[0] = (short)f2bf(br0.x * sc); lo[1] = (short)f2bf(br0.y * sc); \
        lo[2] = (short)f2bf(br0.z * sc); lo[3] = (short)f2bf(br0.w * sc); \
        lo[4] = (short)f2bf(br1.x * sc); lo[5] = (short)f2bf(br1.y * sc); \
        lo[6] = (short)f2bf(br1.z * sc); lo[7] = (short)f2bf(br1.w * sc); \
        hi[0] = (short)f2bf(br2.x * sc); hi[1] = (short)f2bf(br2.y * sc); \
        hi[2] = (short)f2bf(br2.z * sc); hi[3] = (short)f2bf(br2.w * sc); \
        hi[4] = (short)f2bf(br3.x * sc); hi[5] = (short)f2bf(br3.y * sc); \
        hi[6] = (short)f2bf(br3.z * sc); hi[7] = (short)f2bf(br3.w * sc); \
        *(short8*)&Bsl[BUF][q * 2][col][0] = lo;                     \
        *(short8*)&Bsl[BUF][q * 2 + 1][col][0] = hi;                 \
    }

    LOADB(0);
    WRITEB(0);
    LOADB(1);
    __syncthreads();

    for (int kb = 0; kb < 32; ++kb) {
        short8 a0[4], a1[4];
#pragma unroll
        for (int mi = 0; mi < 4; ++mi) {
            a0[mi] = *(const short8*)(ap[mi] + kb * 64);
            a1[mi] = *(const short8*)(ap[mi] + kb * 64 + 32);
        }
        if (kb + 1 < 32) {
            WRITEB((kb + 1) & 1);
            if (kb + 2 < 32) LOADB(kb + 2);
        }
        const int buf = kb & 1;
        short8 bfv[2][4];
#pragma unroll
        for (int s = 0; s < 2; ++s)
#pragma unroll
            for (int ni = 0; ni < 4; ++ni)
                bfv[s][ni] = *(const short8*)&Bsl[buf][s * 4 + kch][ni * 16 + lr][0];
#pragma unroll
        for (int mi = 0; mi < 4; ++mi)
#pragma unroll
            for (int ni = 0; ni < 4; ++ni)
                acc[mi][ni] = __builtin_amdgcn_mfma_f32_16x16x32_bf16(a0[mi], bfv[0][ni], acc[mi][ni], 0, 0, 0);
#pragma unroll
        for (int mi = 0; mi < 4; ++mi)
#pragma unroll
            for (int ni = 0; ni < 4; ++ni)
                acc[mi][ni] = __builtin_amdgcn_mfma_f32_16x16x32_bf16(a1[mi], bfv[1][ni], acc[mi][ni], 0, 0, 0);
        __syncthreads();
    }
#undef LOADB
#undef WRITEB

    const int qq = lane >> 4;
    float bvs[4];
#pragma unroll
    for (int ni = 0; ni < 4; ++ni) bvs[ni] = down_bias[e * HD + n0 + ni * 16 + lr];
#pragma unroll
    for (int mi = 0; mi < 4; ++mi)
#pragma unroll
        for (int j = 0; j < 4; ++j) {
            const int ml = wave * 64 + mi * 16 + qq * 4 + j;
            if (ml >= rows) continue;
            const int slot = base + ml;
            const int tok = tok_slot[slot];
            const float wg = wgt_slot[slot];
            float* orow = out + (size_t)tok * HD;
#pragma unroll
            for (int ni = 0; ni < 4; ++ni)
                atomicAdd(&orow[n0 + ni * 16 + lr], wg * (acc[mi][ni][j] + bvs[ni]));
        }
}

extern "C" void kernel_launch(void* const* d_in, const int* in_sizes, int n_in,
                              void* d_out, int out_size, void* d_ws, size_t ws_size,
                              hipStream_t stream) {
    const float* x           = (const float*)d_in[0];
    const float* rw          = (const float*)d_in[1];
    const float* rb          = (const float*)d_in[2];
    const float* gate_blocks = (const float*)d_in[3];
    const float* gate_scales = (const float*)d_in[4];
    const float* gate_bias   = (const float*)d_in[5];
    const float* up_blocks   = (const float*)d_in[6];
    const float* up_scales   = (const float*)d_in[7];
    const float* up_bias     = (const float*)d_in[8];
    const float* down_blocks = (const float*)d_in[9];
    const float* down_scales = (const float*)d_in[10];
    const float* down_bias   = (const float*)d_in[11];
    float* out = (float*)d_out;

    char* ws = (char*)d_ws;
    u16* xb     = (u16*)ws;                      //  4 MB
    u16* gbuf   = (u16*)(ws + (4 << 20));        // 16 MB
    u16* ubuf   = (u16*)(ws + (20 << 20));       // 16 MB
    u16* hbuf   = (u16*)(ws + (36 << 20));       // 16 MB
    int* counts = (int*)(ws + (52 << 20));       // 16
    int* cursor = counts + 16;                   // 16
    int* basesp = counts + 32;                   // 16
    int* topi   = counts + 64;                   // 4096
    float* topv = (float*)(counts + 64 + 4096);  // 4096
    int* tok_slot = (int*)(counts + 64 + 8192);  // 4096
    float* wgt_slot = (float*)(counts + 64 + 12288);

    hipMemsetAsync(d_out, 0, (size_t)NT * HD * sizeof(float), stream);
    hipMemsetAsync(counts, 0, 128, stream);  // counts + cursor

    router_kernel<<<NT, 64, 0, stream>>>(x, rw, rb, xb, counts, topi, topv);
    bases_kernel<<<1, 64, 0, stream>>>(counts, basesp);
    assign_kernel<<<NT / 256, 256, 0, stream>>>(topi, topv, basesp, cursor, tok_slot, wgt_slot);
    gu_gemm<<<dim3(ID / 64, 4, NE * 2), 256, 0, stream>>>(
        xb, gate_blocks, gate_scales, gate_bias, up_blocks, up_scales, up_bias,
        counts, basesp, tok_slot, gbuf, ubuf);
    act_kernel<<<(NSLOTS * ID / 8) / 256, 256, 0, stream>>>(gbuf, ubuf, hbuf);
    down_gemm<<<dim3(HD / 64, 4, NE), 256, 0, stream>>>(
        hbuf, down_blocks, down_scales, down_bias, counts, basesp, tok_slot, wgt_slot, out);
}